// Round 6
// baseline (123.221 us; speedup 1.0000x reference)
//
#include <hip/hip_runtime.h>

// SoftTree on MI355X — round 6.
// Single-variable change vs R5: GEMM K-loop uses raw s_barrier + counted
// s_waitcnt vmcnt(3) (T4: prefetch stays in flight across barriers) instead of
// __syncthreads() (which drains vmcnt(0) every step). Tree + convert unchanged.
// ws: p f32 [8192][1024] @0, xh fp16 [8192][512] @33.5MB, wh/wl fp16 [1024][512]
//     @41.94/42.99MB. NEED=44,040,192 B else fp32 fallback.

typedef _Float16 f16x8 __attribute__((ext_vector_type(8)));
typedef float f32x4 __attribute__((ext_vector_type(4)));

#define GLOAD16(g, l) __builtin_amdgcn_global_load_lds( \
    (const __attribute__((address_space(1))) void*)(g), \
    (__attribute__((address_space(3))) void*)(l), 16, 0, 0)

// ---------------- conversion: x -> xh fp16; W -> Wt hi/lo fp16 (transposed, padded)
__global__ __launch_bounds__(256) void convert_split(const float* __restrict__ x,
                                                     const float* __restrict__ W,
                                                     _Float16* __restrict__ xh,
                                                     _Float16* __restrict__ wh,
                                                     _Float16* __restrict__ wl)
{
    __shared__ float tile[32][33];
    const int b = blockIdx.x;
    const int tid = threadIdx.x;
    if (b < 1024) {
        const int t = b * 256 + tid;
        const float4* xs = reinterpret_cast<const float4*>(x) + (size_t)t * 4;
        f16x8 o0, o1;
        #pragma unroll
        for (int i = 0; i < 2; ++i) {
            const float4 v0 = xs[i * 2 + 0];
            const float4 v1 = xs[i * 2 + 1];
            f16x8 o;
            o[0] = (_Float16)v0.x; o[1] = (_Float16)v0.y;
            o[2] = (_Float16)v0.z; o[3] = (_Float16)v0.w;
            o[4] = (_Float16)v1.x; o[5] = (_Float16)v1.y;
            o[6] = (_Float16)v1.z; o[7] = (_Float16)v1.w;
            if (i == 0) o0 = o; else o1 = o;
        }
        reinterpret_cast<f16x8*>(xh)[(size_t)t * 2 + 0] = o0;
        reinterpret_cast<f16x8*>(xh)[(size_t)t * 2 + 1] = o1;
    } else {
        const int tb = b - 1024;             // 0..511
        const int k0 = (tb >> 5) * 32;
        const int n0 = (tb & 31) * 32;
        const int tk = tid >> 5, tn = tid & 31;
        #pragma unroll
        for (int j = 0; j < 4; ++j) {
            const int k = k0 + tk + j * 8;
            const int n = n0 + tn;
            tile[tk + j * 8][tn] = (n < 1023) ? W[(size_t)k * 1023 + n] : 0.f;
        }
        __syncthreads();
        const int wn = tid >> 5, wk = tid & 31;
        #pragma unroll
        for (int j = 0; j < 4; ++j) {
            const int n = n0 + wn + j * 8;
            const float v = tile[wk][wn + j * 8];
            const _Float16 h = (_Float16)v;
            const _Float16 lo = (_Float16)(v - (float)h);
            wh[(size_t)n * 512 + k0 + wk] = h;
            wl[(size_t)n * 512 + k0 + wk] = lo;
        }
    }
}

// ---------------- Kernel A: p = sigmoid(x@W + b), fp16 2-product MFMA
// T4 schedule: raw s_barrier pairs; vmcnt(3) keeps newest prefetch in flight.
__global__ __launch_bounds__(512, 4) void gemm_sig_mfma(
    const _Float16* __restrict__ xh,
    const _Float16* __restrict__ wh, const _Float16* __restrict__ wl,
    const float* __restrict__ bias, float* __restrict__ p)
{
    __shared__ __align__(16) _Float16 A_[2][128 * 32];   // 16 KB
    __shared__ __align__(16) _Float16 Bh_[2][128 * 32];  // 16 KB
    __shared__ __align__(16) _Float16 Bl_[2][128 * 32];  // 16 KB

    const int tid = threadIdx.x;
    const int lane = tid & 63;
    const int wv = tid >> 6;            // 0..7
    const int m_base = blockIdx.y * 128;
    const int n_base = blockIdx.x * 128;
    const int wr = wv >> 1, wc = wv & 1; // 4x2 wave grid; wave tile 32x64

    f32x4 acc[2][4];
    #pragma unroll
    for (int i = 0; i < 2; ++i)
        #pragma unroll
        for (int j = 0; j < 4; ++j)
            acc[i][j] = (f32x4){0.f, 0.f, 0.f, 0.f};

    // staging: tile = 512 chunks of 16B (8 halves); one chunk per thread
    const int row = tid >> 2;
    const int oct = (tid & 3) * 8;
    const int lb = wv * 512;            // half-units; HW adds lane*16B
    const size_t ga = (size_t)(m_base + row) * 512 + oct;
    const size_t gb = (size_t)(n_base + row) * 512 + oct;

    const int l15 = lane & 15, kg = lane >> 4;

    #define STAGE(buf, k0) do { \
        GLOAD16(xh + ga + (k0), &A_[buf][lb]);  \
        GLOAD16(wh + gb + (k0), &Bh_[buf][lb]); \
        GLOAD16(wl + gb + (k0), &Bl_[buf][lb]); \
    } while (0)

    STAGE(0, 0);   // 3 loads in flight

    #pragma unroll
    for (int t = 0; t < 16; ++t) {
        const int cur = t & 1;
        // Issue next tile's prefetch, then wait only for the CURRENT tile's
        // 3 loads (the 3 newest stay in flight across the barrier).
        if (t < 15) {
            STAGE(cur ^ 1, (t + 1) * 32);
            asm volatile("s_waitcnt vmcnt(3)" ::: "memory");
        } else {
            asm volatile("s_waitcnt vmcnt(0)" ::: "memory");
        }
        __builtin_amdgcn_sched_barrier(0);
        __builtin_amdgcn_s_barrier();      // B1: buffer `cur` staged by all waves

        f16x8 a_[2], bh_[4], bl_[4];
        #pragma unroll
        for (int mi = 0; mi < 2; ++mi) {
            const int off = (wr * 32 + mi * 16 + l15) * 32 + kg * 8;
            a_[mi] = *reinterpret_cast<const f16x8*>(&A_[cur][off]);
        }
        #pragma unroll
        for (int ni = 0; ni < 4; ++ni) {
            const int off = (wc * 64 + ni * 16 + l15) * 32 + kg * 8;
            bh_[ni] = *reinterpret_cast<const f16x8*>(&Bh_[cur][off]);
            bl_[ni] = *reinterpret_cast<const f16x8*>(&Bl_[cur][off]);
        }
        #pragma unroll
        for (int mi = 0; mi < 2; ++mi)
            #pragma unroll
            for (int ni = 0; ni < 4; ++ni) {
                acc[mi][ni] = __builtin_amdgcn_mfma_f32_16x16x32_f16(a_[mi], bh_[ni], acc[mi][ni], 0, 0, 0);
                acc[mi][ni] = __builtin_amdgcn_mfma_f32_16x16x32_f16(a_[mi], bl_[ni], acc[mi][ni], 0, 0, 0);
            }

        // B2: all waves done reading `cur` before next iter's STAGE overwrites it.
        asm volatile("s_waitcnt lgkmcnt(0)" ::: "memory");  // free (MFMA deps drained)
        __builtin_amdgcn_sched_barrier(0);
        __builtin_amdgcn_s_barrier();
    }
    #undef STAGE

    // epilogue: bias + sigmoid; store SHIFTED: p[m][1+n]
    const int l4 = lane >> 4;
    #pragma unroll
    for (int ni = 0; ni < 4; ++ni) {
        const int n = n_base + wc * 64 + ni * 16 + l15;
        if (n < 1023) {
            const float bv = bias[n];
            #pragma unroll
            for (int mi = 0; mi < 2; ++mi) {
                #pragma unroll
                for (int r = 0; r < 4; ++r) {
                    const int m = m_base + wr * 32 + mi * 16 + l4 * 4 + r;
                    const float v = acc[mi][ni][r] + bv;
                    p[(size_t)m * 1024 + 1 + n] = 1.f / (1.f + __expf(-v));
                }
            }
        }
    }
}

// ---------------- fallback fp32 GEMM (writes shifted p)
__global__ __launch_bounds__(256, 4) void gemm_sig_f32(const float* __restrict__ x,
                                                       const float* __restrict__ W,
                                                       const float* __restrict__ bias,
                                                       float* __restrict__ p)
{
    __shared__ __align__(16) float As[16][128 + 4];
    __shared__ __align__(16) float Bs[16][64 + 4];
    const int tid = threadIdx.x;
    const int m_base = blockIdx.y * 128;
    const int n_base = blockIdx.x * 64;
    const int m0 = (tid >> 4) * 8, n0 = (tid & 15) * 4;
    float acc[8][4];
    #pragma unroll
    for (int i = 0; i < 8; ++i)
        #pragma unroll
        for (int j = 0; j < 4; ++j) acc[i][j] = 0.f;
    const int arow = tid >> 2, acol = (tid & 3) * 4;
    const int bk = tid >> 4, bn = (tid & 15) * 4;
    for (int k0 = 0; k0 < 512; k0 += 16) {
        #pragma unroll
        for (int i = 0; i < 2; ++i) {
            const int row = arow + i * 64;
            const float4 a = *reinterpret_cast<const float4*>(&x[(size_t)(m_base + row) * 512 + k0 + acol]);
            As[0][(acol + 0) * 132 + row] = a.x;
            As[0][(acol + 1) * 132 + row] = a.y;
            As[0][(acol + 2) * 132 + row] = a.z;
            As[0][(acol + 3) * 132 + row] = a.w;
        }
        {
            const int gk = k0 + bk;
            #pragma unroll
            for (int j = 0; j < 4; ++j) {
                const int gn = n_base + bn + j;
                Bs[bk][bn + j] = (gn < 1023) ? W[(size_t)gk * 1023 + gn] : 0.f;
            }
        }
        __syncthreads();
        #pragma unroll
        for (int kk = 0; kk < 16; ++kk) {
            const float4 b4 = *reinterpret_cast<const float4*>(&Bs[kk][n0]);
            const float4 a0 = *reinterpret_cast<const float4*>(&As[kk][m0]);
            const float4 a1 = *reinterpret_cast<const float4*>(&As[kk][m0 + 4]);
            const float a[8] = {a0.x, a0.y, a0.z, a0.w, a1.x, a1.y, a1.z, a1.w};
            const float b[4] = {b4.x, b4.y, b4.z, b4.w};
            #pragma unroll
            for (int i = 0; i < 8; ++i)
                #pragma unroll
                for (int j = 0; j < 4; ++j)
                    acc[i][j] = fmaf(a[i], b[j], acc[i][j]);
        }
        __syncthreads();
    }
    #pragma unroll
    for (int i = 0; i < 8; ++i) {
        const int gm = m_base + m0 + i;
        #pragma unroll
        for (int j = 0; j < 4; ++j) {
            const int gn = n_base + n0 + j;
            if (gn < 1023) {
                float v = acc[i][j] + bias[gn];
                p[(size_t)gm * 1024 + 1 + gn] = 1.0f / (1.0f + __expf(-v));
            }
        }
    }
}

// ---------------- Kernel B: subtree expansion + dot (UNCHANGED from round 3)
__global__ __launch_bounds__(256, 4) void tree_leaves(const float* __restrict__ p,
                                                      const float* __restrict__ leaves,
                                                      float* __restrict__ out)
{
    __shared__ __align__(16) float prob[8][1024];

    const int tid = threadIdx.x;
    const int row_base = blockIdx.x * 8;
    const int r = tid >> 5, s = tid & 31;
    const float* pr = p + (size_t)(row_base + r) * 1024;   // pr[1+node]

    float prefix = 1.f;
    #pragma unroll
    for (int lvl = 0; lvl < 5; ++lvl) {
        const float v = pr[(1 << lvl) + (s >> (5 - lvl))];
        prefix *= ((s >> (4 - lvl)) & 1) ? (1.f - v) : v;
    }

    float q1[2], q2[4], q3[8], q4[16], q5[32];
    {
        const float v = pr[32 + s];
        q1[0] = prefix * v; q1[1] = prefix * (1.f - v);
    }
    {
        const float2 v2 = *reinterpret_cast<const float2*>(&pr[64 + 2 * s]);
        q2[0] = q1[0] * v2.x; q2[1] = q1[0] * (1.f - v2.x);
        q2[2] = q1[1] * v2.y; q2[3] = q1[1] * (1.f - v2.y);
    }
    {
        const float4 v4 = *reinterpret_cast<const float4*>(&pr[128 + 4 * s]);
        const float v[4] = {v4.x, v4.y, v4.z, v4.w};
        #pragma unroll
        for (int j = 0; j < 4; ++j) {
            q3[2 * j] = q2[j] * v[j]; q3[2 * j + 1] = q2[j] * (1.f - v[j]);
        }
    }
    {
        const float4 va = *reinterpret_cast<const float4*>(&pr[256 + 8 * s]);
        const float4 vb = *reinterpret_cast<const float4*>(&pr[260 + 8 * s]);
        const float v[8] = {va.x, va.y, va.z, va.w, vb.x, vb.y, vb.z, vb.w};
        #pragma unroll
        for (int j = 0; j < 8; ++j) {
            q4[2 * j] = q3[j] * v[j]; q4[2 * j + 1] = q3[j] * (1.f - v[j]);
        }
    }
    {
        float v[16];
        #pragma unroll
        for (int u = 0; u < 4; ++u) {
            const float4 vv = *reinterpret_cast<const float4*>(&pr[512 + 16 * s + 4 * u]);
            v[4 * u] = vv.x; v[4 * u + 1] = vv.y; v[4 * u + 2] = vv.z; v[4 * u + 3] = vv.w;
        }
        #pragma unroll
        for (int j = 0; j < 16; ++j) {
            q5[2 * j] = q4[j] * v[j]; q5[2 * j + 1] = q4[j] * (1.f - v[j]);
        }
    }

    const int sw = (s & 7) << 2;
    #pragma unroll
    for (int u = 0; u < 32; u += 4) {
        float4 q; q.x = q5[u]; q.y = q5[u + 1]; q.z = q5[u + 2]; q.w = q5[u + 3];
        *reinterpret_cast<float4*>(&prob[r][s * 32 + (u ^ sw)]) = q;
    }
    __syncthreads();

    const int cg = tid >> 4, dg = tid & 15;
    float acc[8][4];
    #pragma unroll
    for (int i = 0; i < 8; ++i)
        #pragma unroll
        for (int j = 0; j < 4; ++j) acc[i][j] = 0.f;

    #pragma unroll 4
    for (int i4 = 0; i4 < 16; ++i4) {
        const int l0 = cg * 64 + i4 * 4;
        const int m_ = (cg * 2 + (i4 >> 3)) & 7;
        const int col = (cg * 64 + ((i4 * 4) ^ (m_ << 2)));
        float4 lv[4];
        #pragma unroll
        for (int j = 0; j < 4; ++j)
            lv[j] = *reinterpret_cast<const float4*>(&leaves[(size_t)(l0 + j) * 64 + dg * 4]);
        #pragma unroll
        for (int rr = 0; rr < 8; ++rr) {
            const float4 pv = *reinterpret_cast<const float4*>(&prob[rr][col]);
            const float pvv[4] = {pv.x, pv.y, pv.z, pv.w};
            #pragma unroll
            for (int j = 0; j < 4; ++j) {
                acc[rr][0] = fmaf(pvv[j], lv[j].x, acc[rr][0]);
                acc[rr][1] = fmaf(pvv[j], lv[j].y, acc[rr][1]);
                acc[rr][2] = fmaf(pvv[j], lv[j].z, acc[rr][2]);
                acc[rr][3] = fmaf(pvv[j], lv[j].w, acc[rr][3]);
            }
        }
    }

    __syncthreads();
    float* red = &prob[0][0];
    #pragma unroll
    for (int rr = 0; rr < 8; ++rr) {
        float4 q; q.x = acc[rr][0]; q.y = acc[rr][1]; q.z = acc[rr][2]; q.w = acc[rr][3];
        *reinterpret_cast<float4*>(&red[(size_t)(cg * 8 + rr) * 64 + dg * 4]) = q;
    }
    __syncthreads();
    #pragma unroll
    for (int o = tid; o < 512; o += 256) {
        const int rr = o >> 6, d = o & 63;
        float sum = 0.f;
        #pragma unroll
        for (int c = 0; c < 16; ++c)
            sum += red[(size_t)(c * 8 + rr) * 64 + d];
        out[(size_t)(row_base + rr) * 64 + d] = sum;
    }
}

extern "C" void kernel_launch(void* const* d_in, const int* in_sizes, int n_in,
                              void* d_out, int out_size, void* d_ws, size_t ws_size,
                              hipStream_t stream) {
    const float* x      = (const float*)d_in[0];
    const float* W      = (const float*)d_in[1];
    const float* b      = (const float*)d_in[2];
    const float* leaves = (const float*)d_in[3];
    float* out = (float*)d_out;

    float* p = (float*)d_ws;
    const size_t NEED = 44040192;

    if (ws_size >= NEED) {
        _Float16* xh = (_Float16*)((char*)d_ws + 33554432);
        _Float16* wh = (_Float16*)((char*)d_ws + 41943040);
        _Float16* wl = (_Float16*)((char*)d_ws + 42991616);
        convert_split<<<1536, 256, 0, stream>>>(x, W, xh, wh, wl);
        gemm_sig_mfma<<<dim3(8, 64), 512, 0, stream>>>(xh, wh, wl, b, p);
    } else {
        gemm_sig_f32<<<dim3(16, 64), 256, 0, stream>>>(x, W, b, p);
    }
    tree_leaves<<<1024, 256, 0, stream>>>(p, leaves, out);
}